// Round 11
// baseline (140.186 us; speedup 1.0000x reference)
//
#include <hip/hip_runtime.h>

typedef _Float16 half2_t __attribute__((ext_vector_type(2)));
typedef _Float16 half4_t __attribute__((ext_vector_type(4)));
typedef _Float16 half8_t __attribute__((ext_vector_type(8)));
typedef __fp16   fp16x2  __attribute__((ext_vector_type(2)));
typedef float    f32x16  __attribute__((ext_vector_type(16)));

#define BS 128
#define DH 64

static __device__ __forceinline__ half2_t pkrtz(float x, float y) {
  fp16x2 t = __builtin_amdgcn_cvt_pkrtz(x, y);
  return __builtin_bit_cast(half2_t, t);
}
static __device__ __forceinline__ unsigned pkrtz_u(float x, float y) {
  fp16x2 t = __builtin_amdgcn_cvt_pkrtz(x, y);
  return __builtin_bit_cast(unsigned, t);
}

static __device__ __forceinline__ half8_t cvt8(const float4 a, const float4 b) {
  half2_t h0 = pkrtz(a.x, a.y);
  half2_t h1 = pkrtz(a.z, a.w);
  half2_t h2 = pkrtz(b.x, b.y);
  half2_t h3 = pkrtz(b.z, b.w);
  half4_t lo = __builtin_shufflevector(h0, h1, 0, 1, 2, 3);
  half4_t hi = __builtin_shufflevector(h2, h3, 0, 1, 2, 3);
  return __builtin_shufflevector(lo, hi, 0, 1, 2, 3, 4, 5, 6, 7);
}

static __device__ __forceinline__ half8_t h8_from(unsigned r0, unsigned r1,
                                                  unsigned r2, unsigned r3) {
  half2_t h0 = __builtin_bit_cast(half2_t, r0);
  half2_t h1 = __builtin_bit_cast(half2_t, r1);
  half2_t h2 = __builtin_bit_cast(half2_t, r2);
  half2_t h3 = __builtin_bit_cast(half2_t, r3);
  half4_t lo = __builtin_shufflevector(h0, h1, 0, 1, 2, 3);
  half4_t hi = __builtin_shufflevector(h2, h3, 0, 1, 2, 3);
  return __builtin_shufflevector(lo, hi, 0, 1, 2, 3, 4, 5, 6, 7);
}

// (out_lo, out_hi) = (x_lo|y_lo, x_hi|y_hi) across the lane<32 / lane>=32 split.
static __device__ __forceinline__ void plswap(unsigned x, unsigned y,
                                              unsigned& olo, unsigned& ohi) {
#if __has_builtin(__builtin_amdgcn_permlane32_swap)
  auto pr = __builtin_amdgcn_permlane32_swap((int)x, (int)y, false, false);
  unsigned tmp[2];
  __builtin_memcpy(tmp, &pr, 8);
  olo = tmp[0];
  ohi = tmp[1];
#else
  const int h = (threadIdx.x & 63) >> 5;
  unsigned xs = (unsigned)__shfl_xor((int)x, 32);
  unsigned ys = (unsigned)__shfl_xor((int)y, 32);
  olo = h ? ys : x;
  ohi = h ? y : xs;
#endif
}

// VT swizzle: permutation of 0..7 on any 8 consecutive d -> conflict-free for
// the transposed half2 write AND the 32-row b128 PV read.
static __device__ __forceinline__ int svt(int d) { return (d & 7) ^ ((d >> 2) & 7); }

__global__ __launch_bounds__(256) void ball_attn_kernel(
    const float* __restrict__ Q, const float* __restrict__ Kk,
    const float* __restrict__ V, float* __restrict__ O) {
  // ONLY V^T in LDS (16 KB). K is consumed straight from global as A-frags;
  // P stays in registers (cvt_pk + permlane32_swap), softmax is in-lane.
  __shared__ __align__(16) _Float16 VT[DH * BS];

  const int tid  = threadIdx.x;
  const int w    = tid >> 6;   // wave 0..3, owns q rows [32w, 32w+32)
  const int lane = tid & 63;
  const int ld   = lane & 31;  // 32x32 MFMA row/col lane index
  const int hi   = lane >> 5;  // half-wave

  const size_t base = (size_t)blockIdx.x * (BS * DH);
  const float* Qb = Q + base;
  const float* Kb = Kk + base;
  const float* Vb = V + base;
  float*       Ob = O + base;

  // ---- stage V^T (burst of 8 float4, transposed svt-swizzled half2 writes) ----
  {
    const int kgrp = tid >> 4;        // 0..15
    const int d0   = (tid & 15) * 4;  // 0..60
    float4 vA[4], vB[4];
#pragma unroll
    for (int it = 0; it < 4; ++it) {
      const int keyA = 2 * kgrp + 32 * it;
      vA[it] = *(const float4*)(Vb + (size_t)keyA * DH + d0);
      vB[it] = *(const float4*)(Vb + (size_t)(keyA + 1) * DH + d0);
    }
#pragma unroll
    for (int it = 0; it < 4; ++it) {
      const int keyA = 2 * kgrp + 32 * it;
      const float* ap = (const float*)&vA[it];
      const float* bp = (const float*)&vB[it];
#pragma unroll
      for (int j = 0; j < 4; ++j) {
        const int d = d0 + j;
        *(half2_t*)&VT[d * BS + (keyA ^ (svt(d) << 3))] = pkrtz(ap[j], bp[j]);
      }
    }
  }

  // ---- Q as B-fragments: lane holds Q[q=w*32+ld][dstep*16 + hi*8 + 0..7] ----
  half8_t bq[4];
#pragma unroll
  for (int dstep = 0; dstep < 4; ++dstep) {
    const float* qp = Qb + (w * 32 + ld) * DH + dstep * 16 + hi * 8;
    bq[dstep] = cvt8(*(const float4*)qp, *(const float4*)(qp + 4));
  }

  __syncthreads();  // VT visible (only barrier in the kernel)

  // ---- swapped QK^T: acc[kt] = S^T tile, D col = q = ld, row = k(reg,hi) ----
  f32x16 acc[4] = {};
#pragma unroll
  for (int kt = 0; kt < 4; ++kt) {
    const float* krow = Kb + (kt * 32 + ld) * DH + hi * 8;
#pragma unroll
    for (int dstep = 0; dstep < 4; ++dstep) {
      const float* kp = krow + dstep * 16;
      const half8_t ak = cvt8(*(const float4*)kp, *(const float4*)(kp + 4));
      acc[kt] = __builtin_amdgcn_mfma_f32_32x32x16_f16(ak, bq[dstep], acc[kt], 0, 0, 0);
    }
  }

  // ---- softmax, fully in-lane (row q=ld split across the lane-pair) ----
  float mx = acc[0][0];
#pragma unroll
  for (int kt = 0; kt < 4; ++kt)
#pragma unroll
    for (int r = 0; r < 16; ++r) mx = fmaxf(mx, acc[kt][r]);
  mx = fmaxf(mx, __shfl_xor(mx, 32));
  const float nmxs = -mx * 0.125f;
  float sm = 0.f;
#pragma unroll
  for (int kt = 0; kt < 4; ++kt)
#pragma unroll
    for (int r = 0; r < 16; ++r) {
      const float p = __expf(fmaf(acc[kt][r], 0.125f, nmxs));
      acc[kt][r] = p;
      sm += p;
    }
  sm += __shfl_xor(sm, 32);
  const float inv = __builtin_amdgcn_rcpf(sm);  // sum >= 1, safe

  // ---- P -> f16 A-fragments in-register (no LDS):
  // frag[s] element j must be P[q][k=16s+8hi+j]; own regs hold
  // k = kt*32 + 8b + a + 4hi  (reg = 4b+a). j0-3 come from the hi=0 half's
  // quad (kt=s>>1, b=2(s&1)+hi_dst), j4-7 from the hi=1 half's same quad:
  // exactly one permlane32_swap per u32 pair.
  half8_t pf[8];
#pragma unroll
  for (int s = 0; s < 8; ++s) {
    const int kt = s >> 1;
    const int bA = 2 * (s & 1);      // serves hi_dst = 0
    const int bB = bA + 1;           // serves hi_dst = 1
    const unsigned A0 = pkrtz_u(acc[kt][4 * bA + 0] * inv, acc[kt][4 * bA + 1] * inv);
    const unsigned A1 = pkrtz_u(acc[kt][4 * bA + 2] * inv, acc[kt][4 * bA + 3] * inv);
    const unsigned B0 = pkrtz_u(acc[kt][4 * bB + 0] * inv, acc[kt][4 * bB + 1] * inv);
    const unsigned B1 = pkrtz_u(acc[kt][4 * bB + 2] * inv, acc[kt][4 * bB + 3] * inv);
    unsigned r0, r1, r2, r3;
    plswap(A0, B0, r0, r2);
    plswap(A1, B1, r1, r3);
    pf[s] = h8_from(r0, r1, r2, r3);
  }

  // ---- PV: O[q][d] = P·V, A = pf (q rows), B = VT rows d = dt*32+ld ----
  f32x16 o[2] = {};
#pragma unroll
  for (int dt = 0; dt < 2; ++dt) {
    const int row = dt * 32 + ld;
    const int sv  = svt(row) << 3;
#pragma unroll
    for (int s = 0; s < 8; ++s) {
      const half8_t vf = *(const half8_t*)&VT[row * BS + ((16 * s + 8 * hi) ^ sv)];
      o[dt] = __builtin_amdgcn_mfma_f32_32x32x16_f16(pf[s], vf, o[dt], 0, 0, 0);
    }
  }

  // ---- store: col = d = dt*32+ld, row q = w*32 + (reg&3)+8*(reg>>2)+4*hi ----
#pragma unroll
  for (int dt = 0; dt < 2; ++dt)
#pragma unroll
    for (int r = 0; r < 16; ++r) {
      const int qrow = w * 32 + (r & 3) + 8 * (r >> 2) + 4 * hi;
      Ob[qrow * DH + dt * 32 + ld] = o[dt][r];
    }
}

extern "C" void kernel_launch(void* const* d_in, const int* in_sizes, int n_in,
                              void* d_out, int out_size, void* d_ws, size_t ws_size,
                              hipStream_t stream) {
  const float* q = (const float*)d_in[0];
  const float* k = (const float*)d_in[1];
  const float* v = (const float*)d_in[2];
  float* out = (float*)d_out;
  const int nballs = in_sizes[0] / (BS * DH);  // 4096
  ball_attn_kernel<<<dim3(nballs), dim3(256), 0, stream>>>(q, k, v, out);
}

// Round 12
// 120.433 us; speedup vs baseline: 1.1640x; 1.1640x over previous
//
#include <hip/hip_runtime.h>

typedef _Float16 half2_t __attribute__((ext_vector_type(2)));
typedef _Float16 half4_t __attribute__((ext_vector_type(4)));
typedef _Float16 half8_t __attribute__((ext_vector_type(8)));
typedef __fp16   fp16x2  __attribute__((ext_vector_type(2)));
typedef float    f32x16  __attribute__((ext_vector_type(16)));

#define BS 128
#define DH 64

static __device__ __forceinline__ half2_t pkrtz(float x, float y) {
  fp16x2 t = __builtin_amdgcn_cvt_pkrtz(x, y);
  return __builtin_bit_cast(half2_t, t);
}
static __device__ __forceinline__ unsigned pkrtz_u(float x, float y) {
  fp16x2 t = __builtin_amdgcn_cvt_pkrtz(x, y);
  return __builtin_bit_cast(unsigned, t);
}

static __device__ __forceinline__ half8_t cvt8(const float4 a, const float4 b) {
  half2_t h0 = pkrtz(a.x, a.y);
  half2_t h1 = pkrtz(a.z, a.w);
  half2_t h2 = pkrtz(b.x, b.y);
  half2_t h3 = pkrtz(b.z, b.w);
  half4_t lo = __builtin_shufflevector(h0, h1, 0, 1, 2, 3);
  half4_t hi = __builtin_shufflevector(h2, h3, 0, 1, 2, 3);
  return __builtin_shufflevector(lo, hi, 0, 1, 2, 3, 4, 5, 6, 7);
}

static __device__ __forceinline__ half8_t h8_from(unsigned r0, unsigned r1,
                                                  unsigned r2, unsigned r3) {
  half2_t h0 = __builtin_bit_cast(half2_t, r0);
  half2_t h1 = __builtin_bit_cast(half2_t, r1);
  half2_t h2 = __builtin_bit_cast(half2_t, r2);
  half2_t h3 = __builtin_bit_cast(half2_t, r3);
  half4_t lo = __builtin_shufflevector(h0, h1, 0, 1, 2, 3);
  half4_t hi = __builtin_shufflevector(h2, h3, 0, 1, 2, 3);
  return __builtin_shufflevector(lo, hi, 0, 1, 2, 3, 4, 5, 6, 7);
}

// (olo, ohi) = (x_lo|y_lo, x_hi|y_hi) across the lane<32 / lane>=32 split.
static __device__ __forceinline__ void plswap(unsigned x, unsigned y,
                                              unsigned& olo, unsigned& ohi) {
#if __has_builtin(__builtin_amdgcn_permlane32_swap)
  auto pr = __builtin_amdgcn_permlane32_swap((int)x, (int)y, false, false);
  unsigned tmp[2];
  __builtin_memcpy(tmp, &pr, 8);
  olo = tmp[0];
  ohi = tmp[1];
#else
  const int h = (threadIdx.x & 63) >> 5;
  unsigned xs = (unsigned)__shfl_xor((int)x, 32);
  unsigned ys = (unsigned)__shfl_xor((int)y, 32);
  olo = h ? ys : x;
  ohi = h ? y : xs;
#endif
}

// Permutation of 0..7 on any aligned 8-run of d -> conflict-light writes and
// conflict-free b128 reads (verified R9-R11).
static __device__ __forceinline__ int svt(int d) { return (d & 7) ^ ((d >> 2) & 7); }

__global__ __launch_bounds__(256) void ball_attn_kernel(
    const float* __restrict__ Q, const float* __restrict__ Kk,
    const float* __restrict__ V, float* __restrict__ O) {
  // 2 groups x 16 KB V^T = 32 KB. No other LDS. One barrier per block LIFETIME.
  __shared__ __align__(16) _Float16 VT[2][DH * BS];

  const int tid  = threadIdx.x;
  const int w    = tid >> 6;
  const int grp  = w >> 1;   // group 0/1: owns one ball
  const int wg   = w & 1;    // wave within group: q rows [64*wg, 64*wg+64)
  const int lane = tid & 63;
  const int ld   = lane & 31;
  const int hi   = lane >> 5;
  const int gtid = tid & 127;

  // XCD-chunked remap (bijective, 2048 blocks = 8*256)
  const int nwg = gridDim.x;
  const int bid = blockIdx.x;
  const int blk = (bid & 7) * (nwg >> 3) + (bid >> 3);

  const size_t base = ((size_t)blk * 2 + grp) * (BS * DH);
  const float* Qb = Q + base;
  const float* Kb = Kk + base;
  const float* Vb = V + base;
  float*       Ob = O + base;
  _Float16*    vt = VT[grp];

  // ---- stage V^T: group's 128 threads, 2 chunks of 8 independent float4 ----
  {
    const int kgrp = gtid >> 4;        // 0..7
    const int d0   = (gtid & 15) * 4;  // 0..60
#pragma unroll
    for (int half = 0; half < 2; ++half) {
      float4 a[4], b[4];
#pragma unroll
      for (int it2 = 0; it2 < 4; ++it2) {
        const int keyA = 2 * kgrp + 16 * (half * 4 + it2);
        a[it2] = *(const float4*)(Vb + (size_t)keyA * DH + d0);
        b[it2] = *(const float4*)(Vb + (size_t)(keyA + 1) * DH + d0);
      }
#pragma unroll
      for (int it2 = 0; it2 < 4; ++it2) {
        const int keyA = 2 * kgrp + 16 * (half * 4 + it2);
        const float* ap = (const float*)&a[it2];
        const float* bp = (const float*)&b[it2];
#pragma unroll
        for (int j = 0; j < 4; ++j) {
          const int d = d0 + j;
          *(half2_t*)&vt[d * BS + (keyA ^ (svt(d) << 3))] = pkrtz(ap[j], bp[j]);
        }
      }
    }
  }

  __syncthreads();  // only barrier: VT visible to the group's 2 waves

#pragma unroll 1
  for (int qt = 0; qt < 2; ++qt) {
    const int qbase = 64 * wg + 32 * qt;

    // ---- Q burst (8 independent float4 -> 4 B-fragments) ----
    half8_t bq[4];
    {
      float4 qa[4], qb[4];
#pragma unroll
      for (int ds = 0; ds < 4; ++ds) {
        const float* qp = Qb + (qbase + ld) * DH + ds * 16 + hi * 8;
        qa[ds] = *(const float4*)qp;
        qb[ds] = *(const float4*)(qp + 4);
      }
#pragma unroll
      for (int ds = 0; ds < 4; ++ds) bq[ds] = cvt8(qa[ds], qb[ds]);
    }

    // ---- swapped QK^T: acc[kt] = S^T; per-kt 8-deep K load burst ----
    f32x16 acc[4] = {};
#pragma unroll
    for (int kt = 0; kt < 4; ++kt) {
      float4 ka[4], kb[4];
#pragma unroll
      for (int ds = 0; ds < 4; ++ds) {
        const float* kp = Kb + (kt * 32 + ld) * DH + ds * 16 + hi * 8;
        ka[ds] = *(const float4*)kp;
        kb[ds] = *(const float4*)(kp + 4);
      }
#pragma unroll
      for (int ds = 0; ds < 4; ++ds) {
        const half8_t ak = cvt8(ka[ds], kb[ds]);
        acc[kt] = __builtin_amdgcn_mfma_f32_32x32x16_f16(ak, bq[ds], acc[kt], 0, 0, 0);
      }
    }

    // ---- softmax fully in-lane (row q = ld, k split across lane-pair) ----
    float mx = acc[0][0];
#pragma unroll
    for (int kt = 0; kt < 4; ++kt)
#pragma unroll
      for (int r = 0; r < 16; ++r) mx = fmaxf(mx, acc[kt][r]);
    mx = fmaxf(mx, __shfl_xor(mx, 32));
    const float nmxs = -mx * 0.125f;
    float sm = 0.f;
#pragma unroll
    for (int kt = 0; kt < 4; ++kt)
#pragma unroll
      for (int r = 0; r < 16; ++r) {
        const float p = __expf(fmaf(acc[kt][r], 0.125f, nmxs));
        acc[kt][r] = p;
        sm += p;
      }
    sm += __shfl_xor(sm, 32);
    const float inv = __builtin_amdgcn_rcpf(sm);  // sum >= 1, safe

    // ---- P -> f16 A-fragments in-register (cvt_pk + permlane32_swap) ----
    half8_t pf[8];
#pragma unroll
    for (int s = 0; s < 8; ++s) {
      const int kt = s >> 1;
      const int bA = 2 * (s & 1);
      const int bB = bA + 1;
      const unsigned A0 = pkrtz_u(acc[kt][4 * bA + 0] * inv, acc[kt][4 * bA + 1] * inv);
      const unsigned A1 = pkrtz_u(acc[kt][4 * bA + 2] * inv, acc[kt][4 * bA + 3] * inv);
      const unsigned B0 = pkrtz_u(acc[kt][4 * bB + 0] * inv, acc[kt][4 * bB + 1] * inv);
      const unsigned B1 = pkrtz_u(acc[kt][4 * bB + 2] * inv, acc[kt][4 * bB + 3] * inv);
      unsigned r0, r1, r2, r3;
      plswap(A0, B0, r0, r2);
      plswap(A1, B1, r1, r3);
      pf[s] = h8_from(r0, r1, r2, r3);
    }

    // ---- PV from LDS V^T ----
    f32x16 o[2] = {};
#pragma unroll
    for (int dt = 0; dt < 2; ++dt) {
      const int row = dt * 32 + ld;
      const int sv  = svt(row) << 3;
#pragma unroll
      for (int s = 0; s < 8; ++s) {
        const half8_t vf = *(const half8_t*)&vt[row * BS + ((16 * s + 8 * hi) ^ sv)];
        o[dt] = __builtin_amdgcn_mfma_f32_32x32x16_f16(pf[s], vf, o[dt], 0, 0, 0);
      }
    }

    // ---- store: col d = dt*32+ld, row q = qbase + (r&3)+8*(r>>2)+4*hi ----
#pragma unroll
    for (int dt = 0; dt < 2; ++dt)
#pragma unroll
      for (int r = 0; r < 16; ++r) {
        const int qrow = qbase + (r & 3) + 8 * (r >> 2) + 4 * hi;
        Ob[qrow * DH + dt * 32 + ld] = o[dt][r];
      }
  }
}

extern "C" void kernel_launch(void* const* d_in, const int* in_sizes, int n_in,
                              void* d_out, int out_size, void* d_ws, size_t ws_size,
                              hipStream_t stream) {
  const float* q = (const float*)d_in[0];
  const float* k = (const float*)d_in[1];
  const float* v = (const float*)d_in[2];
  float* out = (float*)d_out;
  const int nballs = in_sizes[0] / (BS * DH);  // 4096
  ball_attn_kernel<<<dim3(nballs / 2), dim3(256), 0, stream>>>(q, k, v, out);
}